// Round 4
// baseline (729.426 us; speedup 1.0000x reference)
//
#include <hip/hip_runtime.h>
#include <math.h>

// Problem constants (B=4, D=64, H=W=64 -> m=n=4096)
#define BB 4
#define DD 64
#define MM 4096
#define M1 4097
#define UVST 4104                     // padded u/v row stride
#define NORMC 9.0109133472792788f     // log(8192)
#define LOGHALF -0.69314718055994531f
#define CSH 12.0f                     // fixed shift: E = exp(d - CSH)
#define K2C 21.0109133472792788f      // NORMC + CSH

typedef __attribute__((ext_vector_type(8))) short bf16x8;
typedef __attribute__((ext_vector_type(4))) float f32x4;
typedef __attribute__((ext_vector_type(4))) _Float16 half4;

__device__ __forceinline__ f32x4 mfma16(bf16x8 a, bf16x8 b, f32x4 c) {
    return __builtin_amdgcn_mfma_f32_16x16x32_bf16(a, b, c, 0, 0, 0);
}
__device__ __forceinline__ unsigned short f2bf(float x) {
    unsigned u = __float_as_uint(x);
    u += 0x7fffu + ((u >> 16) & 1u);
    return (unsigned short)(u >> 16);
}
__device__ __forceinline__ float bf2f(unsigned short h) {
    return __uint_as_float(((unsigned)h) << 16);
}
__device__ __forceinline__ void lse_merge(float& m, float& s, float m2, float s2) {
    float M = fmaxf(m, m2);
    s = s * __expf(m - M) + s2 * __expf(m2 - M);
    m = M;
}
__device__ __forceinline__ void lse_add(float& m, float& s, float val) {
    float M = fmaxf(m, val);
    s = s * __expf(m - M) + __expf(val - M);
    m = M;
}

// ===========================================================================
// Shared prep: bf16 hi/lo transposed feats + exact f32 norms
// ===========================================================================
__global__ void __launch_bounds__(256)
prep_kernel(const float* __restrict__ f0, const float* __restrict__ f1,
            unsigned short* __restrict__ h0, unsigned short* __restrict__ l0,
            unsigned short* __restrict__ h1, unsigned short* __restrict__ l1) {
    __shared__ float T[64][65];
    const int b = blockIdx.y;
    const int p0 = blockIdx.x * 64;
    const float* src = (blockIdx.z == 0 ? f0 : f1) + (size_t)b * DD * MM;
    unsigned short* dh = (blockIdx.z == 0 ? h0 : h1) + (size_t)b * MM * DD;
    unsigned short* dl = (blockIdx.z == 0 ? l0 : l1) + (size_t)b * MM * DD;
    const int tid = threadIdx.x;
#pragma unroll
    for (int l = 0; l < 16; ++l) {
        int idx = l * 256 + tid;
        T[idx >> 6][idx & 63] = src[(idx >> 6) * MM + p0 + (idx & 63)];
    }
    __syncthreads();
    const int p = tid >> 2;
    const int cs = (tid & 3) * 16;
    unsigned hw[8], lw[8];
#pragma unroll
    for (int k = 0; k < 8; ++k) {
        float x0 = T[cs + 2 * k][p], x1 = T[cs + 2 * k + 1][p];
        unsigned short a = f2bf(x0), c = f2bf(x1);
        hw[k] = (unsigned)a | ((unsigned)c << 16);
        unsigned short ra = f2bf(x0 - bf2f(a)), rc = f2bf(x1 - bf2f(c));
        lw[k] = (unsigned)ra | ((unsigned)rc << 16);
    }
    size_t base = (size_t)(p0 + p) * DD + cs;
    *(uint4*)(dh + base)     = make_uint4(hw[0], hw[1], hw[2], hw[3]);
    *(uint4*)(dh + base + 8) = make_uint4(hw[4], hw[5], hw[6], hw[7]);
    *(uint4*)(dl + base)     = make_uint4(lw[0], lw[1], lw[2], lw[3]);
    *(uint4*)(dl + base + 8) = make_uint4(lw[4], lw[5], lw[6], lw[7]);
}

__global__ void __launch_bounds__(256)
norms_kernel(const float* __restrict__ f0, const float* __restrict__ f1,
             float* __restrict__ n0, float* __restrict__ n1) {
    int t = blockIdx.x * 256 + threadIdx.x;
    if (t >= BB * MM) return;
    int b = t / MM, p = t % MM;
    const float* s0 = f0 + (size_t)b * DD * MM + p;
    const float* s1 = f1 + (size_t)b * DD * MM + p;
    float a = 0.f, c = 0.f;
#pragma unroll 8
    for (int k = 0; k < DD; ++k) {
        float x = s0[(size_t)k * MM]; a = fmaf(x, x, a);
        float y = s1[(size_t)k * MM]; c = fmaf(y, y, c);
    }
    n0[t] = a; n1[t] = c;
}

// ===========================================================================
// FAST PATH
// E16 layout: tile-major [b][rt(256)][jt(256)][l(64)][e(4)] fp16
// where row = rt*16 + 4*(l>>4)+e, col = jt*16 + (l&15)
// ===========================================================================

// init: u=v=0, W=1
__global__ void __launch_bounds__(256)
init_kernel(float* __restrict__ u, float* __restrict__ v, float* __restrict__ W) {
    int t = blockIdx.x * 256 + threadIdx.x;
    if (t < BB * UVST) { u[t] = 0.f; v[t] = 0.f; }
    if (t < BB * MM) W[t] = 1.0f;
}

// E = exp(dist - CSH), split-precision bf16 MFMA, tile-major coalesced store
__global__ void __launch_bounds__(256)
dist_e16_kernel(const unsigned short* __restrict__ h0, const unsigned short* __restrict__ l0,
                const unsigned short* __restrict__ h1, const unsigned short* __restrict__ l1,
                const float* __restrict__ n0, const float* __restrict__ n1,
                _Float16* __restrict__ E16) {
    const int id = blockIdx.x;
    const int xcd = id & 7, slot = id >> 3;
    const int b = xcd >> 1;
    const int x = slot * 2 + (xcd & 1);
    const int r0 = x * 32;
    const int tid = threadIdx.x;
    const int w = tid >> 6, l = tid & 63, lg = l >> 4, lc = l & 15;
    const size_t fb = (size_t)b * MM * DD;

    bf16x8 Ah[2][2], Al[2][2];
#pragma unroll
    for (int st = 0; st < 2; ++st) {
        const unsigned short* pa = h0 + fb + (size_t)(r0 + st * 16 + lc) * DD + 8 * lg;
        const unsigned short* qa = l0 + fb + (size_t)(r0 + st * 16 + lc) * DD + 8 * lg;
        Ah[st][0] = *(const bf16x8*)pa; Ah[st][1] = *(const bf16x8*)(pa + 32);
        Al[st][0] = *(const bf16x8*)qa; Al[st][1] = *(const bf16x8*)(qa + 32);
    }
    float n0r[2][4];
#pragma unroll
    for (int st = 0; st < 2; ++st)
#pragma unroll
        for (int e = 0; e < 4; ++e)
            n0r[st][e] = n0[b * MM + r0 + st * 16 + 4 * lg + e];

    for (int tt = 0; tt < 64; ++tt) {
        const int j0 = w * 1024 + tt * 16;
        const unsigned short* pb = h1 + fb + (size_t)(j0 + lc) * DD + 8 * lg;
        const unsigned short* qb = l1 + fb + (size_t)(j0 + lc) * DD + 8 * lg;
        bf16x8 Bh0 = *(const bf16x8*)pb, Bh1 = *(const bf16x8*)(pb + 32);
        bf16x8 Bl0 = *(const bf16x8*)qb, Bl1 = *(const bf16x8*)(qb + 32);
        float n1j = n1[b * MM + j0 + lc];
        const int jt = w * 64 + tt;
#pragma unroll
        for (int st = 0; st < 2; ++st) {
            f32x4 acc = {0.f, 0.f, 0.f, 0.f};
            acc = mfma16(Ah[st][0], Bh0, acc);
            acc = mfma16(Ah[st][1], Bh1, acc);
            acc = mfma16(Ah[st][0], Bl0, acc);
            acc = mfma16(Ah[st][1], Bl1, acc);
            acc = mfma16(Al[st][0], Bh0, acc);
            acc = mfma16(Al[st][1], Bh1, acc);
            half4 hv;
#pragma unroll
            for (int e = 0; e < 4; ++e) {
                float d2 = fmaxf(__builtin_fmaf(-2.f, acc[e], n0r[st][e] + n1j), 0.f);
                hv[e] = (_Float16)__expf(sqrtf(d2) - CSH);
            }
            const int rt = x * 2 + st;
            _Float16* dst = E16 + (((size_t)(b * 256 + rt)) * 256 + jt) * 256 + l * 4;
            *(half4*)dst = hv;
        }
    }
}

// Fused Sinkhorn half-iteration: per block (16 rows): u_i from W, then
// column partials with fresh X_i, reusing E chunks held in registers.
__global__ void __launch_bounds__(512)
sink_kernel(const _Float16* __restrict__ E16, const float* __restrict__ Wv,
            const float* __restrict__ v, float* __restrict__ u,
            float* __restrict__ psum, const float* __restrict__ bin) {
    __shared__ float Wl[4096];
    __shared__ float ps1[128];
    __shared__ float Xl[16];
    __shared__ float am[8], as_[8];
    const int bid = blockIdx.x;
    const int tid = threadIdx.x;
    const float bs = *bin;

    if (bid < BB * 256) {
        const int b = bid >> 8, rt = bid & 255;
        const int w = tid >> 6, l = tid & 63, lg = l >> 4, lc = l & 15;
        // stage W
        const float* wb = Wv + b * MM;
#pragma unroll
        for (int k = 0; k < 8; ++k) Wl[k * 512 + tid] = wb[k * 512 + tid];
        __syncthreads();

        const _Float16* EB = E16 + ((size_t)(b * 256 + rt)) * 65536 + (size_t)w * 8192 + l * 4;
        half4 ec[32];
#pragma unroll
        for (int k = 0; k < 32; ++k) ec[k] = *(const half4*)(EB + (size_t)k * 256);

        float rs0 = 0.f, rs1 = 0.f, rs2 = 0.f, rs3 = 0.f;
#pragma unroll
        for (int k = 0; k < 32; ++k) {
            float wv = Wl[(w * 32 + k) * 16 + lc];
            rs0 = fmaf((float)ec[k][0], wv, rs0);
            rs1 = fmaf((float)ec[k][1], wv, rs1);
            rs2 = fmaf((float)ec[k][2], wv, rs2);
            rs3 = fmaf((float)ec[k][3], wv, rs3);
        }
#pragma unroll
        for (int off = 1; off < 16; off <<= 1) {
            rs0 += __shfl_xor(rs0, off);
            rs1 += __shfl_xor(rs1, off);
            rs2 += __shfl_xor(rs2, off);
            rs3 += __shfl_xor(rs3, off);
        }
        if (lc == 0) {
            ps1[w * 16 + 4 * lg + 0] = rs0;
            ps1[w * 16 + 4 * lg + 1] = rs1;
            ps1[w * 16 + 4 * lg + 2] = rs2;
            ps1[w * 16 + 4 * lg + 3] = rs3;
        }
        __syncthreads();
        if (tid < 16) {
            float s = 0.f;
#pragma unroll
            for (int k = 0; k < 8; ++k) s += ps1[k * 16 + tid];
            s += __expf(bs + v[b * UVST + MM] - CSH);      // dustbin column
            float ur = -NORMC - CSH - __logf(s);
            u[b * UVST + rt * 16 + tid] = ur;
            Xl[tid] = __expf(ur);
        }
        __syncthreads();
        // phase 2: column partials over these 16 rows
        const float x0 = Xl[4 * lg], x1 = Xl[4 * lg + 1];
        const float x2 = Xl[4 * lg + 2], x3 = Xl[4 * lg + 3];
        float* po = psum + ((size_t)(b * 256 + rt)) * MM;
#pragma unroll
        for (int k = 0; k < 32; ++k) {
            float p = (float)ec[k][0] * x0 + (float)ec[k][1] * x1
                    + (float)ec[k][2] * x2 + (float)ec[k][3] * x3;
            p += __shfl_xor(p, 16);
            p += __shfl_xor(p, 32);
            if (lg == 0) po[(w * 32 + k) * 16 + lc] = p;
        }
    } else {
        // dustbin row: u[b][4096] = LOGHALF - bs - lse_j(v_j) (exact)
        const int b = bid - BB * 256;
        const int w = tid >> 6, l = tid & 63;
        float m = -INFINITY, s = 0.f;
        for (int t = tid; t < M1; t += 512) lse_add(m, s, v[b * UVST + t]);
#pragma unroll
        for (int off = 1; off < 64; off <<= 1)
            lse_merge(m, s, __shfl_xor(m, off), __shfl_xor(s, off));
        if (l == 0) { am[w] = m; as_[w] = s; }
        __syncthreads();
        if (tid == 0) {
            float M = am[0], S = as_[0];
#pragma unroll
            for (int k = 1; k < 8; ++k) lse_merge(M, S, am[k], as_[k]);
            u[b * UVST + MM] = LOGHALF - bs - (M + __logf(S));
        }
    }
}

// combine chunk partials -> v, W=exp(v); spare blocks: dustbin v[MM]
__global__ void __launch_bounds__(256)
v_comb_kernel(const float* __restrict__ psum, const float* __restrict__ u,
              float* __restrict__ v, float* __restrict__ Wv,
              const float* __restrict__ bin) {
    const int tid = threadIdx.x;
    const int blk = blockIdx.x;
    const float bs = *bin;
    if (blk < 64) {
        int t = blk * 256 + tid;
        int b = t >> 12, j = t & 4095;
        const float* pp = psum + (size_t)b * 256 * MM + j;
        float S = 0.f;
#pragma unroll 8
        for (int c = 0; c < 256; ++c) S += pp[(size_t)c * MM];
        S += __expf(bs + u[b * UVST + MM] - CSH);          // dustbin row
        float vj = -NORMC - CSH - __logf(S);
        v[b * UVST + j] = vj;
        Wv[b * MM + j] = __expf(vj);
    } else {
        const int b = blk - 64;
        const int w = tid >> 6, l = tid & 63;
        float m = -INFINITY, s = 0.f;
        for (int t = tid; t < M1; t += 256) lse_add(m, s, u[b * UVST + t]);
#pragma unroll
        for (int off = 1; off < 64; off <<= 1)
            lse_merge(m, s, __shfl_xor(m, off), __shfl_xor(s, off));
        __shared__ float am[4], as_[4];
        if (l == 0) { am[w] = m; as_[w] = s; }
        __syncthreads();
        if (tid == 0) {
            float M = am[0], S = as_[0];
#pragma unroll
            for (int k = 1; k < 4; ++k) lse_merge(M, S, am[k], as_[k]);
            v[b * UVST + MM] = LOGHALF - bs - (M + __logf(S));
        }
    }
}

// gamma main block: read E tile-major, write row-major via LDS transpose
__global__ void __launch_bounds__(256)
fin_kernel(const _Float16* __restrict__ E16, const float* __restrict__ u,
           const float* __restrict__ v, float* __restrict__ G,
           float* __restrict__ pA) {
    __shared__ float T[16][257];
    __shared__ float vL[4096];
    __shared__ float uL[16];
    const int bid = blockIdx.x;
    const int b = bid >> 8, rt = bid & 255;
    const int tid = threadIdx.x;
#pragma unroll
    for (int k = 0; k < 16; ++k) vL[k * 256 + tid] = v[b * UVST + k * 256 + tid];
    if (tid < 16) uL[tid] = u[b * UVST + rt * 16 + tid] + K2C;
    __syncthreads();

    const _Float16* EB = E16 + ((size_t)(b * 256 + rt)) * 65536;
    float pm = 0.f, pr = 0.f;
    for (int sb = 0; sb < 16; ++sb) {
#pragma unroll
        for (int q = 0; q < 4; ++q) {
            int c = q * 256 + tid;
            int jr = c >> 6, l = c & 63, lg = l >> 4, lc = l & 15;
            half4 h = *(const half4*)(EB + ((size_t)(sb * 16 + jr)) * 256 + l * 4);
            float vv = vL[(sb * 16 + jr) * 16 + lc];
#pragma unroll
            for (int e = 0; e < 4; ++e) {
                float Ef = (float)h[e];
                float g = Ef * __expf(uL[4 * lg + e] + vv);
                T[4 * lg + e][jr * 16 + lc] = g;
                pm = fmaf(g, CSH + __logf(Ef), pm);
                pr += g;
            }
        }
        __syncthreads();
        float* gb = G + ((size_t)(b * M1 + rt * 16)) * M1 + sb * 256;
#pragma unroll
        for (int r = 0; r < 16; ++r) gb[(size_t)r * M1 + tid] = T[r][tid];
        __syncthreads();
    }
#pragma unroll
    for (int off = 1; off < 64; off <<= 1) {
        pm += __shfl_xor(pm, off);
        pr += __shfl_xor(pr, off);
    }
    __shared__ float s0[4], s1[4];
    if ((tid & 63) == 0) { s0[tid >> 6] = pm; s1[tid >> 6] = pr; }
    __syncthreads();
    if (tid == 0) {
        pA[bid * 2 + 0] = s0[0] + s0[1] + s0[2] + s0[3];
        pA[bid * 2 + 1] = s1[0] + s1[1] + s1[2] + s1[3];
    }
}

// last row + last col + corner of gamma (uvst parameterized for both paths)
__global__ void __launch_bounds__(256)
fin_edge_kernel(const float* __restrict__ u, const float* __restrict__ v,
                const float* __restrict__ bin, float* __restrict__ G,
                float* __restrict__ pB, int uvst) {
    const float bs = *bin;
    int t = blockIdx.x * 256 + threadIdx.x;
    float pc = 0.f, pr = 0.f;
    if (t < BB * M1) {
        int b = t / M1, j = t % M1;
        float g = __expf(bs + u[b * uvst + MM] + v[b * uvst + j] + NORMC);
        G[((size_t)b * M1 + MM) * M1 + j] = g;
        if (j == MM) pc += g;
    } else if (t < BB * M1 + BB * MM) {
        int q = t - BB * M1;
        int b = q / MM, i = q % MM;
        float g = __expf(bs + u[b * uvst + i] + v[b * uvst + MM] + NORMC);
        G[((size_t)b * M1 + i) * M1 + MM] = g;
        pc += g; pr += g;
    }
#pragma unroll
    for (int off = 1; off < 64; off <<= 1) {
        pc += __shfl_xor(pc, off);
        pr += __shfl_xor(pr, off);
    }
    __shared__ float s0[4], s1[4];
    int tid = threadIdx.x;
    if ((tid & 63) == 0) { s0[tid >> 6] = pc; s1[tid >> 6] = pr; }
    __syncthreads();
    if (tid == 0) {
        pB[blockIdx.x * 2 + 0] = s0[0] + s0[1] + s0[2] + s0[3];
        pB[blockIdx.x * 2 + 1] = s1[0] + s1[1] + s1[2] + s1[3];
    }
}

__global__ void __launch_bounds__(256)
reduce_out_kernel(const float* __restrict__ pA, int nA,
                  const float* __restrict__ pB, int nB, float* __restrict__ out) {
    const int tid = threadIdx.x;
    float pm = 0.f, prA = 0.f, pc = 0.f, prB = 0.f;
    for (int r = tid; r < nA; r += 256) { pm += pA[2 * r]; prA += pA[2 * r + 1]; }
    for (int r = tid; r < nB; r += 256) { pc += pB[2 * r]; prB += pB[2 * r + 1]; }
#pragma unroll
    for (int off = 1; off < 64; off <<= 1) {
        pm += __shfl_xor(pm, off);
        prA += __shfl_xor(prA, off);
        pc += __shfl_xor(pc, off);
        prB += __shfl_xor(prB, off);
    }
    __shared__ float a0[4], a1[4], a2[4], a3[4];
    if ((tid & 63) == 0) {
        int w = tid >> 6;
        a0[w] = pm; a1[w] = prA; a2[w] = pc; a3[w] = prB;
    }
    __syncthreads();
    if (tid == 0) {
        float PM = a0[0] + a0[1] + a0[2] + a0[3];
        float PRA = a1[0] + a1[1] + a1[2] + a1[3];
        float PC = a2[0] + a2[1] + a2[2] + a2[3];
        float PRB = a3[0] + a3[1] + a3[2] + a3[3];
        out[0] = PM / (4.0f * 4096.0f);
        out[1] = PC / (4.0f * 4097.0f) + (PRA + PRB) / (4.0f * 4096.0f * 4097.0f);
    }
}

// ===========================================================================
// FALLBACK (round-2 recompute path, ~8.7 MB ws) — used only if ws too small
// ===========================================================================
__global__ void __launch_bounds__(256)
upass_kernel(const unsigned short* __restrict__ h0, const unsigned short* __restrict__ l0,
             const unsigned short* __restrict__ h1, const unsigned short* __restrict__ l1,
             const float* __restrict__ n0, const float* __restrict__ n1,
             const float* __restrict__ v, float* __restrict__ u,
             const float* __restrict__ bin) {
    const int id = blockIdx.x;
    const int xcd = id & 7, slot = id >> 3;
    const int b = xcd >> 1;
    const int x = slot * 2 + (xcd & 1);
    const int r0 = x * 32;
    const float bs = *bin;
    const float* vb = v + b * M1;
    const int tid = threadIdx.x;
    const int w = tid >> 6, l = tid & 63, lg = l >> 4, lc = l & 15;
    const size_t fb = (size_t)b * MM * DD;
    bf16x8 Ah[2][2], Al[2][2];
#pragma unroll
    for (int st = 0; st < 2; ++st) {
        const unsigned short* pa = h0 + fb + (size_t)(r0 + st * 16 + lc) * DD + 8 * lg;
        const unsigned short* qa = l0 + fb + (size_t)(r0 + st * 16 + lc) * DD + 8 * lg;
        Ah[st][0] = *(const bf16x8*)pa; Ah[st][1] = *(const bf16x8*)(pa + 32);
        Al[st][0] = *(const bf16x8*)qa; Al[st][1] = *(const bf16x8*)(qa + 32);
    }
    float n0r[2][4], m[2][4], s[2][4];
#pragma unroll
    for (int st = 0; st < 2; ++st)
#pragma unroll
        for (int e = 0; e < 4; ++e) {
            n0r[st][e] = n0[b * MM + r0 + st * 16 + 4 * lg + e];
            m[st][e] = -INFINITY; s[st][e] = 0.f;
        }
    for (int tt = 0; tt < 64; ++tt) {
        const int j0 = w * 1024 + tt * 16;
        const unsigned short* pb = h1 + fb + (size_t)(j0 + lc) * DD + 8 * lg;
        const unsigned short* qb = l1 + fb + (size_t)(j0 + lc) * DD + 8 * lg;
        bf16x8 Bh0 = *(const bf16x8*)pb, Bh1 = *(const bf16x8*)(pb + 32);
        bf16x8 Bl0 = *(const bf16x8*)qb, Bl1 = *(const bf16x8*)(qb + 32);
        float n1j = n1[b * MM + j0 + lc];
        float vj = vb[j0 + lc];
#pragma unroll
        for (int st = 0; st < 2; ++st) {
            f32x4 acc = {0.f, 0.f, 0.f, 0.f};
            acc = mfma16(Ah[st][0], Bh0, acc);
            acc = mfma16(Ah[st][1], Bh1, acc);
            acc = mfma16(Ah[st][0], Bl0, acc);
            acc = mfma16(Ah[st][1], Bl1, acc);
            acc = mfma16(Al[st][0], Bh0, acc);
            acc = mfma16(Al[st][1], Bh1, acc);
#pragma unroll
            for (int e = 0; e < 4; ++e) {
                float d2 = fmaxf(__builtin_fmaf(-2.f, acc[e], n0r[st][e] + n1j), 0.f);
                lse_add(m[st][e], s[st][e], sqrtf(d2) + vj);
            }
        }
    }
#pragma unroll
    for (int off = 1; off < 16; off <<= 1)
#pragma unroll
        for (int st = 0; st < 2; ++st)
#pragma unroll
            for (int e = 0; e < 4; ++e)
                lse_merge(m[st][e], s[st][e], __shfl_xor(m[st][e], off), __shfl_xor(s[st][e], off));
    __shared__ float lm[4][32], lsx[4][32];
    if (lc == 0) {
#pragma unroll
        for (int st = 0; st < 2; ++st)
#pragma unroll
            for (int e = 0; e < 4; ++e) {
                lm[w][st * 16 + 4 * lg + e] = m[st][e];
                lsx[w][st * 16 + 4 * lg + e] = s[st][e];
            }
    }
    __syncthreads();
    if (tid < 32) {
        float M = lm[0][tid], S = lsx[0][tid];
#pragma unroll
        for (int k = 1; k < 4; ++k) lse_merge(M, S, lm[k][tid], lsx[k][tid]);
        lse_add(M, S, bs + vb[MM]);
        u[b * M1 + r0 + tid] = -NORMC - (M + __logf(S));
    }
    if (x == 0) {
        float dm = -INFINITY, dsv = 0.f;
        for (int j = tid; j < M1; j += 256) lse_add(dm, dsv, vb[j]);
#pragma unroll
        for (int off = 1; off < 64; off <<= 1)
            lse_merge(dm, dsv, __shfl_xor(dm, off), __shfl_xor(dsv, off));
        __shared__ float am[4], asv[4];
        if (l == 0) { am[w] = dm; asv[w] = dsv; }
        __syncthreads();
        if (tid == 0) {
            float M = am[0], S = asv[0];
#pragma unroll
            for (int k = 1; k < 4; ++k) lse_merge(M, S, am[k], asv[k]);
            u[b * M1 + MM] = LOGHALF - (bs + M + __logf(S));
        }
    }
}

__global__ void __launch_bounds__(256)
vpass_kernel(const unsigned short* __restrict__ h0, const unsigned short* __restrict__ l0,
             const unsigned short* __restrict__ h1, const unsigned short* __restrict__ l1,
             const float* __restrict__ n0, const float* __restrict__ n1,
             const float* __restrict__ u, float* __restrict__ v,
             const float* __restrict__ bin) {
    const int id = blockIdx.x;
    const int xcd = id & 7, slot = id >> 3;
    const int b = xcd >> 1;
    const int x = slot * 2 + (xcd & 1);
    const int j0 = x * 32;
    const float bs = *bin;
    const float* ub = u + b * M1;
    const int tid = threadIdx.x;
    const int w = tid >> 6, l = tid & 63, lg = l >> 4, lc = l & 15;
    const size_t fb = (size_t)b * MM * DD;
    bf16x8 Bh[2][2], Bl[2][2];
#pragma unroll
    for (int st = 0; st < 2; ++st) {
        const unsigned short* pb = h1 + fb + (size_t)(j0 + st * 16 + lc) * DD + 8 * lg;
        const unsigned short* qb = l1 + fb + (size_t)(j0 + st * 16 + lc) * DD + 8 * lg;
        Bh[st][0] = *(const bf16x8*)pb; Bh[st][1] = *(const bf16x8*)(pb + 32);
        Bl[st][0] = *(const bf16x8*)qb; Bl[st][1] = *(const bf16x8*)(qb + 32);
    }
    float n1c[2] = { n1[b * MM + j0 + lc], n1[b * MM + j0 + 16 + lc] };
    float m[2] = { -INFINITY, -INFINITY }, s[2] = { 0.f, 0.f };
    for (int tt = 0; tt < 64; ++tt) {
        const int i0 = w * 1024 + tt * 16;
        const unsigned short* pa = h0 + fb + (size_t)(i0 + lc) * DD + 8 * lg;
        const unsigned short* qa = l0 + fb + (size_t)(i0 + lc) * DD + 8 * lg;
        bf16x8 Ah0 = *(const bf16x8*)pa, Ah1 = *(const bf16x8*)(pa + 32);
        bf16x8 Al0 = *(const bf16x8*)qa, Al1 = *(const bf16x8*)(qa + 32);
        float uw[4], nw[4];
#pragma unroll
        for (int e = 0; e < 4; ++e) {
            int row = i0 + 4 * lg + e;
            uw[e] = ub[row];
            nw[e] = n0[b * MM + row];
        }
#pragma unroll
        for (int st = 0; st < 2; ++st) {
            f32x4 acc = {0.f, 0.f, 0.f, 0.f};
            acc = mfma16(Ah0, Bh[st][0], acc);
            acc = mfma16(Ah1, Bh[st][1], acc);
            acc = mfma16(Ah0, Bl[st][0], acc);
            acc = mfma16(Ah1, Bl[st][1], acc);
            acc = mfma16(Al0, Bh[st][0], acc);
            acc = mfma16(Al1, Bh[st][1], acc);
#pragma unroll
            for (int e = 0; e < 4; ++e) {
                float d2 = fmaxf(__builtin_fmaf(-2.f, acc[e], nw[e] + n1c[st]), 0.f);
                lse_add(m[st], s[st], sqrtf(d2) + uw[e]);
            }
        }
    }
#pragma unroll
    for (int off = 16; off < 64; off <<= 1)
#pragma unroll
        for (int st = 0; st < 2; ++st)
            lse_merge(m[st], s[st], __shfl_xor(m[st], off), __shfl_xor(s[st], off));
    __shared__ float lmv[4][2][16], lsv[4][2][16];
    if (l < 16) {
#pragma unroll
        for (int st = 0; st < 2; ++st) { lmv[w][st][l] = m[st]; lsv[w][st][l] = s[st]; }
    }
    __syncthreads();
    if (tid < 32) {
        int st = tid >> 4, c = tid & 15;
        float M = lmv[0][st][c], S = lsv[0][st][c];
#pragma unroll
        for (int k = 1; k < 4; ++k) lse_merge(M, S, lmv[k][st][c], lsv[k][st][c]);
        lse_add(M, S, bs + ub[MM]);
        v[b * M1 + j0 + st * 16 + c] = -NORMC - (M + __logf(S));
    }
    if (x == 0) {
        float dm = -INFINITY, dsv = 0.f;
        for (int i = tid; i < M1; i += 256) lse_add(dm, dsv, ub[i]);
#pragma unroll
        for (int off = 1; off < 64; off <<= 1)
            lse_merge(dm, dsv, __shfl_xor(dm, off), __shfl_xor(dsv, off));
        __shared__ float am[4], asv[4];
        if (l == 0) { am[w] = dm; asv[w] = dsv; }
        __syncthreads();
        if (tid == 0) {
            float M = am[0], S = asv[0];
#pragma unroll
            for (int k = 1; k < 4; ++k) lse_merge(M, S, am[k], asv[k]);
            v[b * M1 + MM] = LOGHALF - (bs + M + __logf(S));
        }
    }
}

__global__ void __launch_bounds__(256)
fin_rec_kernel(const unsigned short* __restrict__ h0, const unsigned short* __restrict__ l0,
               const unsigned short* __restrict__ h1, const unsigned short* __restrict__ l1,
               const float* __restrict__ n0, const float* __restrict__ n1,
               const float* __restrict__ u, const float* __restrict__ v,
               float* __restrict__ G, float* __restrict__ pA) {
    const int id = blockIdx.x;
    const int xcd = id & 7, slot = id >> 3;
    const int b = xcd >> 1;
    const int x = slot * 2 + (xcd & 1);
    const int r0 = x * 32;
    const float* vb = v + b * M1;
    const int tid = threadIdx.x;
    const int w = tid >> 6, l = tid & 63, lg = l >> 4, lc = l & 15;
    const size_t fb = (size_t)b * MM * DD;
    bf16x8 Ah[2][2], Al[2][2];
#pragma unroll
    for (int st = 0; st < 2; ++st) {
        const unsigned short* pa = h0 + fb + (size_t)(r0 + st * 16 + lc) * DD + 8 * lg;
        const unsigned short* qa = l0 + fb + (size_t)(r0 + st * 16 + lc) * DD + 8 * lg;
        Ah[st][0] = *(const bf16x8*)pa; Ah[st][1] = *(const bf16x8*)(pa + 32);
        Al[st][0] = *(const bf16x8*)qa; Al[st][1] = *(const bf16x8*)(qa + 32);
    }
    float n0r[2][4], ur[2][4];
#pragma unroll
    for (int st = 0; st < 2; ++st)
#pragma unroll
        for (int e = 0; e < 4; ++e) {
            int row = r0 + st * 16 + 4 * lg + e;
            n0r[st][e] = n0[b * MM + row];
            ur[st][e] = u[b * M1 + row];
        }
    float pm = 0.f, pr = 0.f;
    for (int tt = 0; tt < 64; ++tt) {
        const int j0 = w * 1024 + tt * 16;
        const unsigned short* pb = h1 + fb + (size_t)(j0 + lc) * DD + 8 * lg;
        const unsigned short* qb = l1 + fb + (size_t)(j0 + lc) * DD + 8 * lg;
        bf16x8 Bh0 = *(const bf16x8*)pb, Bh1 = *(const bf16x8*)(pb + 32);
        bf16x8 Bl0 = *(const bf16x8*)qb, Bl1 = *(const bf16x8*)(qb + 32);
        float n1j = n1[b * MM + j0 + lc];
        float vj = vb[j0 + lc];
#pragma unroll
        for (int st = 0; st < 2; ++st) {
            f32x4 acc = {0.f, 0.f, 0.f, 0.f};
            acc = mfma16(Ah[st][0], Bh0, acc);
            acc = mfma16(Ah[st][1], Bh1, acc);
            acc = mfma16(Ah[st][0], Bl0, acc);
            acc = mfma16(Ah[st][1], Bl1, acc);
            acc = mfma16(Al[st][0], Bh0, acc);
            acc = mfma16(Al[st][1], Bh1, acc);
#pragma unroll
            for (int e = 0; e < 4; ++e) {
                float d2 = fmaxf(__builtin_fmaf(-2.f, acc[e], n0r[st][e] + n1j), 0.f);
                float d = sqrtf(d2);
                float g = __expf(d + ur[st][e] + vj + NORMC);
                int row = r0 + st * 16 + 4 * lg + e;
                G[((size_t)(b * M1 + row)) * M1 + j0 + lc] = g;
                pm = fmaf(g, d, pm);
                pr += g;
            }
        }
    }
#pragma unroll
    for (int off = 1; off < 64; off <<= 1) {
        pm += __shfl_xor(pm, off);
        pr += __shfl_xor(pr, off);
    }
    __shared__ float s0[4], s1[4];
    if (l == 0) { s0[w] = pm; s1[w] = pr; }
    __syncthreads();
    if (tid == 0) {
        pA[id * 2 + 0] = s0[0] + s0[1] + s0[2] + s0[3];
        pA[id * 2 + 1] = s1[0] + s1[1] + s1[2] + s1[3];
    }
}

// ===========================================================================
extern "C" void kernel_launch(void* const* d_in, const int* in_sizes, int n_in,
                              void* d_out, int out_size, void* d_ws, size_t ws_size,
                              hipStream_t stream) {
    const float* feat0 = (const float*)d_in[0];
    const float* feat1 = (const float*)d_in[1];
    const float* bin   = (const float*)d_in[2];
    float* out = (float*)d_out;
    float* G   = out + 2;                      // gamma region [4][4097][4097]
    float* ws  = (float*)d_ws;

    // fast-path ws layout (float offsets)
    const size_t OF_U   = 0;                   // 16416
    const size_t OF_V   = 16416;               // 16416
    const size_t OF_W   = 32832;               // 16384
    const size_t OF_N0  = 49216;               // 16384
    const size_t OF_N1  = 65600;               // 16384
    const size_t OF_PA  = 81984;               // 2048
    const size_t OF_PB  = 84032;               // 258 (+pad)
    const size_t OF_PS  = 84304;               // 4*256*4096 = 4194304
    const size_t OF_BF  = 4278608;             // 4 x 1M ushorts = 2097152 floats
    const size_t OF_E16 = 6375760;             // 67108864 fp16 = 33554432 floats
    const size_t NEED = (OF_E16 + 33554432) * 4;

    if (ws_size >= NEED) {
        float* u  = ws + OF_U;
        float* v  = ws + OF_V;
        float* Wv = ws + OF_W;
        float* n0 = ws + OF_N0;
        float* n1 = ws + OF_N1;
        float* pA = ws + OF_PA;
        float* pB = ws + OF_PB;
        float* psum = ws + OF_PS;
        unsigned short* h0 = (unsigned short*)(ws + OF_BF);
        unsigned short* l0 = h0 + 1048576;
        unsigned short* h1 = l0 + 1048576;
        unsigned short* l1 = h1 + 1048576;
        _Float16* E16 = (_Float16*)(ws + OF_E16);

        init_kernel<<<65, 256, 0, stream>>>(u, v, Wv);
        prep_kernel<<<dim3(64, BB, 2), 256, 0, stream>>>(feat0, feat1, h0, l0, h1, l1);
        norms_kernel<<<64, 256, 0, stream>>>(feat0, feat1, n0, n1);
        dist_e16_kernel<<<512, 256, 0, stream>>>(h0, l0, h1, l1, n0, n1, E16);
        for (int it = 0; it < 10; ++it) {
            sink_kernel<<<BB * 256 + BB, 512, 0, stream>>>(E16, Wv, v, u, psum, bin);
            v_comb_kernel<<<64 + BB, 256, 0, stream>>>(psum, u, v, Wv, bin);
        }
        fin_kernel<<<1024, 256, 0, stream>>>(E16, u, v, G, pA);
        fin_edge_kernel<<<129, 256, 0, stream>>>(u, v, bin, G, pB, UVST);
        reduce_out_kernel<<<1, 256, 0, stream>>>(pA, 1024, pB, 129, out);
    } else {
        // fallback: recompute path (~8.7 MB ws)
        float* u  = ws;                          // 16388
        float* v  = ws + 16388;                  // 16388
        float* n0 = ws + 32776;                  // 16384
        float* n1 = ws + 49160;                  // 16384
        float* pA = ws + 65544;                  // 1024
        float* pB = ws + 66568;                  // 264
        unsigned short* h0 = (unsigned short*)(ws + 66832);
        unsigned short* l0 = h0 + 1048576;
        unsigned short* h1 = l0 + 1048576;
        unsigned short* l1 = h1 + 1048576;

        hipMemsetAsync(ws, 0, 32776 * sizeof(float), stream);
        prep_kernel<<<dim3(64, BB, 2), 256, 0, stream>>>(feat0, feat1, h0, l0, h1, l1);
        norms_kernel<<<64, 256, 0, stream>>>(feat0, feat1, n0, n1);
        for (int it = 0; it < 10; ++it) {
            upass_kernel<<<512, 256, 0, stream>>>(h0, l0, h1, l1, n0, n1, v, u, bin);
            vpass_kernel<<<512, 256, 0, stream>>>(h0, l0, h1, l1, n0, n1, u, v, bin);
        }
        fin_rec_kernel<<<512, 256, 0, stream>>>(h0, l0, h1, l1, n0, n1, u, v, G, pA);
        fin_edge_kernel<<<129, 256, 0, stream>>>(u, v, bin, G, pB, M1);
        reduce_out_kernel<<<1, 256, 0, stream>>>(pA, 512, pB, 129, out);
    }
}

// Round 5
// 543.873 us; speedup vs baseline: 1.3412x; 1.3412x over previous
//
#include <hip/hip_runtime.h>
#include <math.h>

// Problem constants (B=4, D=64, H=W=64 -> m=n=4096)
#define BB 4
#define DD 64
#define MM 4096
#define M1 4097
#define NORMC 9.0109133472792788f     // log(8192)
#define CSH 10.0f                     // E = exp(d - CSH)

typedef __attribute__((ext_vector_type(8))) short bf16x8;
typedef __attribute__((ext_vector_type(4))) float f32x4;
typedef __attribute__((ext_vector_type(4))) _Float16 half4;

__device__ __forceinline__ f32x4 mfma16(bf16x8 a, bf16x8 b, f32x4 c) {
    return __builtin_amdgcn_mfma_f32_16x16x32_bf16(a, b, c, 0, 0, 0);
}
__device__ __forceinline__ unsigned short f2bf(float x) {
    unsigned u = __float_as_uint(x);
    u += 0x7fffu + ((u >> 16) & 1u);
    return (unsigned short)(u >> 16);
}
__device__ __forceinline__ float bf2f(unsigned short h) {
    return __uint_as_float(((unsigned)h) << 16);
}

// ===========================================================================
// prep: transpose feats to [b][p][c] bf16 hi/lo; norms: exact f32 |x|^2
// ===========================================================================
__global__ void __launch_bounds__(256)
prep_kernel(const float* __restrict__ f0, const float* __restrict__ f1,
            unsigned short* __restrict__ h0, unsigned short* __restrict__ l0,
            unsigned short* __restrict__ h1, unsigned short* __restrict__ l1) {
    __shared__ float T[64][65];
    const int b = blockIdx.y;
    const int p0 = blockIdx.x * 64;
    const float* src = (blockIdx.z == 0 ? f0 : f1) + (size_t)b * DD * MM;
    unsigned short* dh = (blockIdx.z == 0 ? h0 : h1) + (size_t)b * MM * DD;
    unsigned short* dl = (blockIdx.z == 0 ? l0 : l1) + (size_t)b * MM * DD;
    const int tid = threadIdx.x;
#pragma unroll
    for (int l = 0; l < 16; ++l) {
        int idx = l * 256 + tid;
        T[idx >> 6][idx & 63] = src[(idx >> 6) * MM + p0 + (idx & 63)];
    }
    __syncthreads();
    const int p = tid >> 2;
    const int cs = (tid & 3) * 16;
    unsigned hw[8], lw[8];
#pragma unroll
    for (int k = 0; k < 8; ++k) {
        float x0 = T[cs + 2 * k][p], x1 = T[cs + 2 * k + 1][p];
        unsigned short a = f2bf(x0), c = f2bf(x1);
        hw[k] = (unsigned)a | ((unsigned)c << 16);
        unsigned short ra = f2bf(x0 - bf2f(a)), rc = f2bf(x1 - bf2f(c));
        lw[k] = (unsigned)ra | ((unsigned)rc << 16);
    }
    size_t base = (size_t)(p0 + p) * DD + cs;
    *(uint4*)(dh + base)     = make_uint4(hw[0], hw[1], hw[2], hw[3]);
    *(uint4*)(dh + base + 8) = make_uint4(hw[4], hw[5], hw[6], hw[7]);
    *(uint4*)(dl + base)     = make_uint4(lw[0], lw[1], lw[2], lw[3]);
    *(uint4*)(dl + base + 8) = make_uint4(lw[4], lw[5], lw[6], lw[7]);
}

__global__ void __launch_bounds__(256)
norms_kernel(const float* __restrict__ f0, const float* __restrict__ f1,
             float* __restrict__ n0, float* __restrict__ n1) {
    int t = blockIdx.x * 256 + threadIdx.x;
    if (t >= BB * MM) return;
    int b = t / MM, p = t % MM;
    const float* s0 = f0 + (size_t)b * DD * MM + p;
    const float* s1 = f1 + (size_t)b * DD * MM + p;
    float a = 0.f, c = 0.f;
#pragma unroll 8
    for (int k = 0; k < DD; ++k) {
        float x = s0[(size_t)k * MM]; a = fmaf(x, x, a);
        float y = s1[(size_t)k * MM]; c = fmaf(y, y, c);
    }
    n0[t] = a; n1[t] = c;
}

// init: W = 1, S = {X_MM[4], W_MM[4]} = 1
__global__ void __launch_bounds__(256)
init_kernel(float* __restrict__ W, float* __restrict__ S) {
    int t = blockIdx.x * 256 + threadIdx.x;
    if (t < BB * MM) W[t] = 1.0f;
    if (t < 8) S[t] = 1.0f;
}

// ===========================================================================
// E16 = exp(dist - CSH), tile-major [b][rt(256)][jt(256)][l*4+e] fp16
// where row = rt*16 + 4*(l>>4)+e, col = jt*16 + (l&15)
// ===========================================================================
__global__ void __launch_bounds__(256)
dist_e16_kernel(const unsigned short* __restrict__ h0, const unsigned short* __restrict__ l0,
                const unsigned short* __restrict__ h1, const unsigned short* __restrict__ l1,
                const float* __restrict__ n0, const float* __restrict__ n1,
                _Float16* __restrict__ E16) {
    const int id = blockIdx.x;
    const int xcd = id & 7, slot = id >> 3;
    const int b = xcd >> 1;
    const int x = slot * 2 + (xcd & 1);
    const int r0 = x * 32;
    const int tid = threadIdx.x;
    const int w = tid >> 6, l = tid & 63, lg = l >> 4, lc = l & 15;
    const size_t fb = (size_t)b * MM * DD;

    bf16x8 Ah[2][2], Al[2][2];
#pragma unroll
    for (int st = 0; st < 2; ++st) {
        const unsigned short* pa = h0 + fb + (size_t)(r0 + st * 16 + lc) * DD + 8 * lg;
        const unsigned short* qa = l0 + fb + (size_t)(r0 + st * 16 + lc) * DD + 8 * lg;
        Ah[st][0] = *(const bf16x8*)pa; Ah[st][1] = *(const bf16x8*)(pa + 32);
        Al[st][0] = *(const bf16x8*)qa; Al[st][1] = *(const bf16x8*)(qa + 32);
    }
    float n0r[2][4];
#pragma unroll
    for (int st = 0; st < 2; ++st)
#pragma unroll
        for (int e = 0; e < 4; ++e)
            n0r[st][e] = n0[b * MM + r0 + st * 16 + 4 * lg + e];

    for (int tt = 0; tt < 64; ++tt) {
        const int j0 = w * 1024 + tt * 16;
        const unsigned short* pb = h1 + fb + (size_t)(j0 + lc) * DD + 8 * lg;
        const unsigned short* qb = l1 + fb + (size_t)(j0 + lc) * DD + 8 * lg;
        bf16x8 Bh0 = *(const bf16x8*)pb, Bh1 = *(const bf16x8*)(pb + 32);
        bf16x8 Bl0 = *(const bf16x8*)qb, Bl1 = *(const bf16x8*)(qb + 32);
        float n1j = n1[b * MM + j0 + lc];
        const int jt = w * 64 + tt;
#pragma unroll
        for (int st = 0; st < 2; ++st) {
            f32x4 acc = {0.f, 0.f, 0.f, 0.f};
            acc = mfma16(Ah[st][0], Bh0, acc);
            acc = mfma16(Ah[st][1], Bh1, acc);
            acc = mfma16(Ah[st][0], Bl0, acc);
            acc = mfma16(Ah[st][1], Bl1, acc);
            acc = mfma16(Al[st][0], Bh0, acc);
            acc = mfma16(Al[st][1], Bh1, acc);
            half4 hv;
#pragma unroll
            for (int e = 0; e < 4; ++e) {
                float d2 = fmaxf(__builtin_fmaf(-2.f, acc[e], n0r[st][e] + n1j), 0.f);
                hv[e] = (_Float16)__expf(sqrtf(d2) - CSH);
            }
            const int rt = x * 2 + st;
            _Float16* dst = E16 + (((size_t)(b * 256 + rt)) * 256 + jt) * 256 + l * 4;
            *(half4*)dst = hv;
        }
    }
}

// ===========================================================================
// Multiplicative Sinkhorn iteration (no per-element transcendentals)
// sink: per block = 64 rows: X_i = K/((E.W)_i + Ebin*W_MM); column partials
//       accumulate in registers across the 4 sub-tiles -> psum[b][rb][4096]
// ===========================================================================
__global__ void __launch_bounds__(512)
sink_kernel(const _Float16* __restrict__ E16, const float* __restrict__ W,
            float* __restrict__ X, float* __restrict__ S,
            float* __restrict__ psum, const float* __restrict__ bin) {
    const int bid = blockIdx.x;
    const int tid = threadIdx.x;
    const float bs = *bin;
    if (bid < BB * 64) {
        __shared__ float Wl[4096];
        __shared__ float ps1[128];
        __shared__ float XL[16];
        const int b = bid >> 6, rb = bid & 63;
        const int w = tid >> 6, l = tid & 63, lg = l >> 4, lc = l & 15;
#pragma unroll
        for (int k = 0; k < 8; ++k) Wl[k * 512 + tid] = W[b * MM + k * 512 + tid];
        const float wmm_term = __expf(bs - CSH) * S[4 + b];
        const float KC = __expf(-NORMC - CSH);
        __syncthreads();
        float acc[32];
#pragma unroll
        for (int k = 0; k < 32; ++k) acc[k] = 0.f;
        for (int st = 0; st < 4; ++st) {
            const int rt = rb * 4 + st;
            const _Float16* EB = E16 + ((size_t)(b * 256 + rt)) * 65536 + w * 8192 + l * 4;
            half4 ec[32];
#pragma unroll
            for (int k = 0; k < 32; ++k) ec[k] = *(const half4*)(EB + (size_t)k * 256);
            float rs0 = 0.f, rs1 = 0.f, rs2 = 0.f, rs3 = 0.f;
#pragma unroll
            for (int k = 0; k < 32; ++k) {
                float wv = Wl[(w * 32 + k) * 16 + lc];
                rs0 = fmaf((float)ec[k][0], wv, rs0);
                rs1 = fmaf((float)ec[k][1], wv, rs1);
                rs2 = fmaf((float)ec[k][2], wv, rs2);
                rs3 = fmaf((float)ec[k][3], wv, rs3);
            }
#pragma unroll
            for (int off = 1; off < 16; off <<= 1) {
                rs0 += __shfl_xor(rs0, off);
                rs1 += __shfl_xor(rs1, off);
                rs2 += __shfl_xor(rs2, off);
                rs3 += __shfl_xor(rs3, off);
            }
            if (lc == 0) {
                ps1[w * 16 + 4 * lg + 0] = rs0;
                ps1[w * 16 + 4 * lg + 1] = rs1;
                ps1[w * 16 + 4 * lg + 2] = rs2;
                ps1[w * 16 + 4 * lg + 3] = rs3;
            }
            __syncthreads();
            if (tid < 16) {
                float s = 0.f;
#pragma unroll
                for (int k = 0; k < 8; ++k) s += ps1[k * 16 + tid];
                float xv = KC / (s + wmm_term);
                X[b * MM + rt * 16 + tid] = xv;
                XL[tid] = xv;
            }
            __syncthreads();
            const float x0 = XL[4 * lg + 0], x1 = XL[4 * lg + 1];
            const float x2 = XL[4 * lg + 2], x3 = XL[4 * lg + 3];
#pragma unroll
            for (int k = 0; k < 32; ++k) {
                float p = fmaf((float)ec[k][0], x0, (float)ec[k][1] * x1);
                p = fmaf((float)ec[k][2], x2, p);
                p = fmaf((float)ec[k][3], x3, p);
                acc[k] += p;
            }
        }
        float* po = psum + ((size_t)(b * 64 + rb)) * MM;
#pragma unroll
        for (int k = 0; k < 32; ++k) {
            float r = acc[k];
            r += __shfl_xor(r, 16);
            r += __shfl_xor(r, 32);
            if (lg == 0) po[(w * 32 + k) * 16 + lc] = r;
        }
    } else {
        // X_MM[b] = 0.5 e^{-bs} / (sum_j W_j + W_MM[b])
        const int b = bid - BB * 64;
        const int w = tid >> 6, l = tid & 63;
        __shared__ float am[8];
        float s = 0.f;
        for (int t = tid; t < MM; t += 512) s += W[b * MM + t];
#pragma unroll
        for (int off = 1; off < 64; off <<= 1) s += __shfl_xor(s, off);
        if (l == 0) am[w] = s;
        __syncthreads();
        if (tid == 0) {
            float tot = 0.f;
#pragma unroll
            for (int k = 0; k < 8; ++k) tot += am[k];
            S[b] = 0.5f * __expf(-bs) / (tot + S[4 + b]);
        }
    }
}

// combine column partials -> W; extra blocks: W_MM
__global__ void __launch_bounds__(256)
wcomb_kernel(const float* __restrict__ psum, const float* __restrict__ X,
             float* __restrict__ W, float* __restrict__ S,
             const float* __restrict__ bin) {
    const int bid = blockIdx.x;
    const int tid = threadIdx.x;
    const float bs = *bin;
    if (bid < BB * 64) {
        __shared__ float ps[256];
        const int b = bid >> 6, cg = bid & 63;
        const int col = cg * 64 + (tid & 63);
        const int grp = tid >> 6;
        const float* pp = psum + (size_t)b * 64 * MM + col;
        float s = 0.f;
#pragma unroll
        for (int c = 0; c < 16; ++c) s += pp[(size_t)(grp * 16 + c) * MM];
        ps[tid] = s;
        __syncthreads();
        if (tid < 64) {
            float c = ps[tid] + ps[tid + 64] + ps[tid + 128] + ps[tid + 192];
            c += __expf(bs - CSH) * S[b];                 // dustbin-row term
            W[b * MM + cg * 64 + tid] = __expf(-NORMC - CSH) / c;
        }
    } else {
        // W_MM[b] = 0.5 e^{-bs} / (sum_i X_i + X_MM[b])
        const int b = bid - BB * 64;
        const int w = tid >> 6, l = tid & 63;
        __shared__ float am[4];
        float s = 0.f;
        for (int t = tid; t < MM; t += 256) s += X[b * MM + t];
#pragma unroll
        for (int off = 1; off < 64; off <<= 1) s += __shfl_xor(s, off);
        if (l == 0) am[w] = s;
        __syncthreads();
        if (tid == 0) {
            float tot = am[0] + am[1] + am[2] + am[3];
            S[4 + b] = 0.5f * __expf(-bs) / (tot + S[b]);
        }
    }
}

// ===========================================================================
// gamma main block: g = E * X_i * W_j * e^{NORMC+CSH}; loss partials
// ===========================================================================
__global__ void __launch_bounds__(256)
fin_kernel(const _Float16* __restrict__ E16, const float* __restrict__ X,
           const float* __restrict__ W, float* __restrict__ G,
           float* __restrict__ pA) {
    __shared__ float T[16][257];
    __shared__ float WL[4096];
    __shared__ float XL[16];
    const int bid = blockIdx.x;
    const int b = bid >> 8, rt = bid & 255;
    const int tid = threadIdx.x;
#pragma unroll
    for (int k = 0; k < 16; ++k) WL[k * 256 + tid] = W[b * MM + k * 256 + tid];
    if (tid < 16) XL[tid] = X[b * MM + rt * 16 + tid] * __expf(NORMC + CSH);
    __syncthreads();

    const _Float16* EB = E16 + ((size_t)(b * 256 + rt)) * 65536;
    float pm = 0.f, pr = 0.f;
    for (int sb = 0; sb < 16; ++sb) {
#pragma unroll
        for (int q = 0; q < 4; ++q) {
            int c = q * 256 + tid;
            int jr = c >> 6, l = c & 63, lg = l >> 4, lc = l & 15;
            half4 h = *(const half4*)(EB + ((size_t)(sb * 16 + jr)) * 256 + l * 4);
            float wv = WL[(sb * 16 + jr) * 16 + lc];
#pragma unroll
            for (int e = 0; e < 4; ++e) {
                float Ef = (float)h[e];
                float g = Ef * XL[4 * lg + e] * wv;
                T[4 * lg + e][jr * 16 + lc] = g;
                pm = fmaf(g, CSH + __logf(Ef), pm);   // d = CSH + log(E)
                pr += g;
            }
        }
        __syncthreads();
        float* gb = G + ((size_t)(b * M1 + rt * 16)) * M1 + sb * 256;
#pragma unroll
        for (int r = 0; r < 16; ++r) gb[(size_t)r * M1 + tid] = T[r][tid];
        __syncthreads();
    }
#pragma unroll
    for (int off = 1; off < 64; off <<= 1) {
        pm += __shfl_xor(pm, off);
        pr += __shfl_xor(pr, off);
    }
    __shared__ float s0[4], s1[4];
    if ((tid & 63) == 0) { s0[tid >> 6] = pm; s1[tid >> 6] = pr; }
    __syncthreads();
    if (tid == 0) {
        pA[bid * 2 + 0] = s0[0] + s0[1] + s0[2] + s0[3];
        pA[bid * 2 + 1] = s1[0] + s1[1] + s1[2] + s1[3];
    }
}

// last row + last col + corner of gamma; loss partials
__global__ void __launch_bounds__(256)
fin_edge_kernel(const float* __restrict__ X, const float* __restrict__ W,
                const float* __restrict__ S, const float* __restrict__ bin,
                float* __restrict__ G, float* __restrict__ pB) {
    const float bs = *bin;
    const float CC = __expf(NORMC + bs);
    int t = blockIdx.x * 256 + threadIdx.x;
    float pc = 0.f, pr = 0.f;
    if (t < BB * M1) {
        int b = t / M1, j = t % M1;
        float wj = (j < MM) ? W[b * MM + j] : S[4 + b];
        float g = CC * S[b] * wj;                      // dustbin row
        G[((size_t)b * M1 + MM) * M1 + j] = g;
        if (j == MM) pc += g;                          // corner
    } else if (t < BB * M1 + BB * MM) {
        int q = t - BB * M1;
        int b = q / MM, i = q % MM;
        float g = CC * X[b * MM + i] * S[4 + b];       // dustbin col
        G[((size_t)b * M1 + i) * M1 + MM] = g;
        pc += g; pr += g;
    }
#pragma unroll
    for (int off = 1; off < 64; off <<= 1) {
        pc += __shfl_xor(pc, off);
        pr += __shfl_xor(pr, off);
    }
    __shared__ float s0[4], s1[4];
    int tid = threadIdx.x;
    if ((tid & 63) == 0) { s0[tid >> 6] = pc; s1[tid >> 6] = pr; }
    __syncthreads();
    if (tid == 0) {
        pB[blockIdx.x * 2 + 0] = s0[0] + s0[1] + s0[2] + s0[3];
        pB[blockIdx.x * 2 + 1] = s1[0] + s1[1] + s1[2] + s1[3];
    }
}

__global__ void __launch_bounds__(256)
reduce_out_kernel(const float* __restrict__ pA, int nA,
                  const float* __restrict__ pB, int nB, float* __restrict__ out) {
    const int tid = threadIdx.x;
    float pm = 0.f, prA = 0.f, pc = 0.f, prB = 0.f;
    for (int r = tid; r < nA; r += 256) { pm += pA[2 * r]; prA += pA[2 * r + 1]; }
    for (int r = tid; r < nB; r += 256) { pc += pB[2 * r]; prB += pB[2 * r + 1]; }
#pragma unroll
    for (int off = 1; off < 64; off <<= 1) {
        pm += __shfl_xor(pm, off);
        prA += __shfl_xor(prA, off);
        pc += __shfl_xor(pc, off);
        prB += __shfl_xor(prB, off);
    }
    __shared__ float a0[4], a1[4], a2[4], a3[4];
    if ((tid & 63) == 0) {
        int w = tid >> 6;
        a0[w] = pm; a1[w] = prA; a2[w] = pc; a3[w] = prB;
    }
    __syncthreads();
    if (tid == 0) {
        float PM = a0[0] + a0[1] + a0[2] + a0[3];
        float PRA = a1[0] + a1[1] + a1[2] + a1[3];
        float PC = a2[0] + a2[1] + a2[2] + a2[3];
        float PRB = a3[0] + a3[1] + a3[2] + a3[3];
        out[0] = PM / (4.0f * 4096.0f);
        out[1] = PC / (4.0f * 4097.0f) + (PRA + PRB) / (4.0f * 4096.0f * 4097.0f);
    }
}

// ===========================================================================
extern "C" void kernel_launch(void* const* d_in, const int* in_sizes, int n_in,
                              void* d_out, int out_size, void* d_ws, size_t ws_size,
                              hipStream_t stream) {
    const float* feat0 = (const float*)d_in[0];
    const float* feat1 = (const float*)d_in[1];
    const float* bin   = (const float*)d_in[2];
    float* out = (float*)d_out;
    float* G   = out + 2;                      // gamma region [4][4097][4097]
    float* ws  = (float*)d_ws;

    // ws layout (float offsets), ~147 MB total
    const size_t OF_X   = 0;                   // 16384
    const size_t OF_W   = 16384;               // 16384
    const size_t OF_S   = 32768;               // 8  (X_MM[4], W_MM[4]) + pad
    const size_t OF_PA  = 32784;               // 2048
    const size_t OF_PB  = 34832;               // 272
    const size_t OF_PS  = 35104;               // 4*64*4096 = 1048576
    const size_t OF_BF  = 1083680;             // 4 x 1M ushorts = 2097152 floats
    const size_t OF_E16 = 3180832;             // 67108864 fp16 = 33554432 floats

    float* X  = ws + OF_X;
    float* W  = ws + OF_W;
    float* S  = ws + OF_S;
    float* pA = ws + OF_PA;
    float* pB = ws + OF_PB;
    float* psum = ws + OF_PS;
    unsigned short* h0 = (unsigned short*)(ws + OF_BF);
    unsigned short* l0 = h0 + 1048576;
    unsigned short* h1 = l0 + 1048576;
    unsigned short* l1 = h1 + 1048576;
    _Float16* E16 = (_Float16*)(ws + OF_E16);
    float* n0 = psum;                          // reuse psum region for norms
    float* n1 = psum + 16384;                  // (consumed before psum is written)

    init_kernel<<<64, 256, 0, stream>>>(W, S);
    prep_kernel<<<dim3(64, BB, 2), 256, 0, stream>>>(feat0, feat1, h0, l0, h1, l1);
    norms_kernel<<<64, 256, 0, stream>>>(feat0, feat1, n0, n1);
    dist_e16_kernel<<<512, 256, 0, stream>>>(h0, l0, h1, l1, n0, n1, E16);
    for (int it = 0; it < 10; ++it) {
        sink_kernel<<<BB * 64 + BB, 512, 0, stream>>>(E16, W, X, S, psum, bin);
        wcomb_kernel<<<BB * 64 + BB, 256, 0, stream>>>(psum, X, W, S, bin);
    }
    fin_kernel<<<1024, 256, 0, stream>>>(E16, X, W, G, pA);
    fin_edge_kernel<<<129, 256, 0, stream>>>(X, W, S, bin, G, pB);
    reduce_out_kernel<<<1, 256, 0, stream>>>(pA, 1024, pB, 129, out);
}